// Round 4
// baseline (999.194 us; speedup 1.0000x reference)
//
#include <hip/hip_runtime.h>
#include <cstdint>

#define ROTL32(v,n) (((v) << (n)) | ((v) >> (32 - (n))))

// ---- JAX threefry-2x32 (20 rounds, exact key-injection schedule) ----
__host__ __device__ __forceinline__ void tf2x32(uint32_t k0, uint32_t k1,
                                                uint32_t x0, uint32_t x1,
                                                uint32_t& o0, uint32_t& o1)
{
  uint32_t k2 = k0 ^ k1 ^ 0x1BD11BDAu;
  x0 += k0; x1 += k1;
#define TF_RND(r) { x0 += x1; x1 = ROTL32(x1, (r)); x1 ^= x0; }
  TF_RND(13) TF_RND(15) TF_RND(26) TF_RND(6)
  x0 += k1; x1 += k2 + 1u;
  TF_RND(17) TF_RND(29) TF_RND(16) TF_RND(24)
  x0 += k2; x1 += k0 + 2u;
  TF_RND(13) TF_RND(15) TF_RND(26) TF_RND(6)
  x0 += k0; x1 += k1 + 3u;
  TF_RND(17) TF_RND(29) TF_RND(16) TF_RND(24)
  x0 += k1; x1 += k2 + 4u;
  TF_RND(13) TF_RND(15) TF_RND(26) TF_RND(6)
  x0 += k2; x1 += k0 + 5u;
#undef TF_RND
  o0 = x0; o1 = x1;
}

typedef __attribute__((ext_vector_type(8))) _Float16 h16x8;
typedef __attribute__((ext_vector_type(4))) float fl32x4;

__device__ __forceinline__ float u2unit_p(uint32_t b) {
  uint32_t r = (b >> 9) | 0x3F800000u;
  float f; __builtin_memcpy(&f, &r, 4); return f - 1.0f;
}

// ---- x convert + pad: (65536,784) f32 -> (65536,832) fp16, zero cols 784..831 ----
__global__ __launch_bounds__(256) void cvt_x_p(const float* __restrict__ x,
                                               _Float16* __restrict__ xp)
{
  int idx = blockIdx.x * 256 + threadIdx.x;   // 65536*104 chunks of 8
  int row = idx / 104, c = idx - row * 104;
  h16x8 o = {0,0,0,0,0,0,0,0};
  if (c < 98) {
    const fl32x4* p = (const fl32x4*)&x[row * 784 + c * 8];
    fl32x4 a = p[0], b = p[1];
    o[0] = (_Float16)a[0]; o[1] = (_Float16)a[1]; o[2] = (_Float16)a[2]; o[3] = (_Float16)a[3];
    o[4] = (_Float16)b[0]; o[5] = (_Float16)b[1]; o[6] = (_Float16)b[2]; o[7] = (_Float16)b[3];
  }
  *(h16x8*)&xp[row * 832 + c * 8] = o;
}

// ---- weight transpose+convert: W(K,N) f32 -> WT(N,K) fp16 (W1 padded to K=832) ----
__global__ __launch_bounds__(256) void cvt_w_p(
    const float* __restrict__ W1, const float* __restrict__ W2, const float* __restrict__ W3,
    const float* __restrict__ W4, const float* __restrict__ W5, const float* __restrict__ W6,
    const float* __restrict__ W7, _Float16* __restrict__ WT1, _Float16* __restrict__ WT)
{
  int b = blockIdx.x;
  if (b < 1666) {                              // 512*832 = 426496 elems
    int idx = b * 256 + threadIdx.x;           // n*832 + k
    int n = idx / 832, k = idx - n * 832;
    WT1[idx] = (k < 784) ? (_Float16)W1[k * 512 + n] : (_Float16)0.f;
  } else {                                     // 6 layers of 512*512
    int l = (b - 1666) >> 10;
    int idx = ((b - 1666) & 1023) * 256 + threadIdx.x;
    int n = idx >> 9, k = idx & 511;
    const float* Wp = (l == 0) ? W2 : (l == 1) ? W3 : (l == 2) ? W4
                    : (l == 3) ? W5 : (l == 4) ? W6 : W7;
    WT[l * 262144 + idx] = (_Float16)Wp[k * 512 + n];
  }
}

// ---- dropout mask bits, JAX threefry_partitionable path (default since 0.4.36):
//      element j draw = word0 ^ word1 of threefry(dkL, (hi,lo)=(0,j)); keep = u(draw) < q
__global__ __launch_bounds__(256) void mask_gen_p(unsigned long long* __restrict__ m,
    uint32_t k00, uint32_t k01, uint32_t k10, uint32_t k11, uint32_t k20, uint32_t k21)
{
  uint32_t gw   = blockIdx.x * 4u + (threadIdx.x >> 6);  // global wave, 3*2^19 total
  uint32_t lane = threadIdx.x & 63u;
  uint32_t layer = gw >> 19;                   // 2^19 waves (= 2^25 elems) per layer
  uint32_t widx  = gw & 0x7FFFFu;
  uint32_t j     = widx * 64u + lane;          // element index in (65536,512) flat
  uint32_t ka = (layer == 0) ? k00 : (layer == 1) ? k10 : k20;
  uint32_t kb = (layer == 0) ? k01 : (layer == 1) ? k11 : k21;
  float q = (layer == 0) ? 0.8f : (layer == 1) ? 0.7f : 0.5f;
  uint32_t b1, b2;
  tf2x32(ka, kb, 0u, j, b1, b2);
  unsigned long long w = __ballot(u2unit_p(b1 ^ b2) < q);
  if (lane == 0) m[(size_t)layer * 524288u + widx] = w;
}

// ---- 128x128 tile fp16 MFMA GEMM, C = relu(drop?(A@W + b)), A:MxK, BT:NxK ----
template<bool DROP>
__global__ __launch_bounds__(256) void gemm_p(
    const _Float16* __restrict__ A, const _Float16* __restrict__ BT,
    const float* __restrict__ bias, const unsigned long long* __restrict__ mask,
    float invq, _Float16* __restrict__ C, int K)
{
  __shared__ __align__(16) _Float16 Als[128 * 64];
  __shared__ __align__(16) _Float16 Bls[128 * 64];
  int tid = threadIdx.x;
  int lane = tid & 63;
  int wv = tid >> 6;
  int wr = wv >> 1, wc = wv & 1;
  // bijective XCD swizzle: 2048 blocks, 8 XCDs, 256/XCD; consecutive tiles
  // (4 N-tiles sharing an A panel) land on the same XCD's L2.
  int lid = blockIdx.x;
  int t = (lid & 7) * 256 + (lid >> 3);
  int bm = (t >> 2) * 128;
  int bn = (t & 3) * 128;

  const _Float16* Ab = A + (size_t)bm * K;
  const _Float16* Bb = BT + (size_t)bn * K;

  fl32x4 acc[4][4];
#pragma unroll
  for (int i = 0; i < 4; ++i)
#pragma unroll
    for (int j = 0; j < 4; ++j)
      acc[i][j] = (fl32x4){0.f, 0.f, 0.f, 0.f};

  int nsteps = K >> 6;
  for (int kt = 0; kt < nsteps; ++kt) {
#pragma unroll
    for (int p = 0; p < 4; ++p) {              // reg-staged: 1024 16B chunks / 256 thr
      int id = p * 256 + tid;
      int row = id >> 3, c = id & 7;
      int gcol = kt * 64 + c * 8;
      *(h16x8*)&Als[row * 64 + c * 8] = *(const h16x8*)&Ab[(size_t)row * K + gcol];
      *(h16x8*)&Bls[row * 64 + c * 8] = *(const h16x8*)&Bb[(size_t)row * K + gcol];
    }
    __syncthreads();
#pragma unroll
    for (int kk = 0; kk < 2; ++kk) {
      int ko = kk * 32 + (lane >> 4) * 8;
      h16x8 af[4], bfr[4];
#pragma unroll
      for (int m = 0; m < 4; ++m)
        af[m] = *(const h16x8*)&Als[(wr * 64 + m * 16 + (lane & 15)) * 64 + ko];
#pragma unroll
      for (int n = 0; n < 4; ++n)
        bfr[n] = *(const h16x8*)&Bls[(wc * 64 + n * 16 + (lane & 15)) * 64 + ko];
#pragma unroll
      for (int m = 0; m < 4; ++m)
#pragma unroll
        for (int n = 0; n < 4; ++n)
          acc[m][n] = __builtin_amdgcn_mfma_f32_16x16x32_f16(af[m], bfr[n], acc[m][n], 0, 0, 0);
    }
    __syncthreads();
  }

  // epilogue: bias + (dropout) + relu -> fp16. C/D map: col=lane&15, row=(lane>>4)*4+reg
  int c0 = bn + wc * 64 + (lane & 15);
  int r0 = bm + wr * 64 + (lane >> 4) * 4;
#pragma unroll
  for (int n = 0; n < 4; ++n) {
    int col = c0 + n * 16;
    float bv = bias[col];
#pragma unroll
    for (int m = 0; m < 4; ++m) {
#pragma unroll
      for (int r = 0; r < 4; ++r) {
        int row = r0 + m * 16 + r;
        float v = acc[m][n][r] + bv;
        if (DROP) {
          uint32_t j = (uint32_t)row * 512u + (uint32_t)col;
          unsigned long long mw = mask[j >> 6];
          v = ((mw >> (j & 63)) & 1ull) ? v * invq : 0.0f;
        }
        v = fmaxf(v, 0.0f);
        C[(size_t)row * 512 + col] = (_Float16)v;
      }
    }
  }
}

// ---- head: logits = h@W8 + b8 (512->10), softmax, fp32 out ----
__global__ __launch_bounds__(256) void head_p(
    const _Float16* __restrict__ H, const float* __restrict__ W8,
    const float* __restrict__ b8, float* __restrict__ out)
{
  __shared__ float Wl[5120];                   // 512x10 fp32
  for (int i = threadIdx.x; i < 5120; i += 256) Wl[i] = W8[i];
  __syncthreads();
  int lane = threadIdx.x & 63;
  int wv = threadIdx.x >> 6;
  int row = blockIdx.x * 4 + wv;               // one row per wave
  h16x8 h = *(const h16x8*)&H[(size_t)row * 512 + lane * 8];
  float acc[10];
#pragma unroll
  for (int n = 0; n < 10; ++n) acc[n] = 0.f;
#pragma unroll
  for (int j = 0; j < 8; ++j) {
    float hf = (float)h[j];
    const float* wrow = &Wl[(lane * 8 + j) * 10];
#pragma unroll
    for (int n = 0; n < 10; ++n) acc[n] += hf * wrow[n];
  }
#pragma unroll
  for (int off = 1; off < 64; off <<= 1) {
#pragma unroll
    for (int n = 0; n < 10; ++n) acc[n] += __shfl_xor(acc[n], off);
  }
  if (lane == 0) {
    float mx = -3.0e38f;
#pragma unroll
    for (int n = 0; n < 10; ++n) { acc[n] += b8[n]; mx = fmaxf(mx, acc[n]); }
    float s = 0.f, e[10];
#pragma unroll
    for (int n = 0; n < 10; ++n) { e[n] = expf(acc[n] - mx); s += e[n]; }
    float is = 1.0f / s;
#pragma unroll
    for (int n = 0; n < 10; ++n) out[(size_t)row * 10 + n] = e[n] * is;
  }
}

extern "C" void kernel_launch(void* const* d_in, const int* in_sizes, int n_in,
                              void* d_out, int out_size, void* d_ws, size_t ws_size,
                              hipStream_t stream) {
  (void)in_sizes; (void)n_in; (void)out_size; (void)ws_size;
  const float* x = (const float*)d_in[0];
  const float* W[8]; const float* B[8];
  for (int i = 0; i < 8; ++i) { W[i] = (const float*)d_in[1 + 2*i]; B[i] = (const float*)d_in[2 + 2*i]; }

  char* w = (char*)d_ws;                       // ~248 MB total
  _Float16* xpad = (_Float16*)(w);             // 65536*832 fp16   = 109,051,904 B
  _Float16* hA   = (_Float16*)(w + 109051904); // 65536*512 fp16   =  67,108,864 B
  _Float16* hB   = (_Float16*)(w + 176160768); // 65536*512 fp16   =  67,108,864 B
  _Float16* WT1  = (_Float16*)(w + 243269632); // 512*832 fp16     =     851,968 B
  _Float16* WT   = (_Float16*)(w + 244121600); // 6 x 512*512 fp16 =   3,145,728 B
  unsigned long long* masks = (unsigned long long*)(w + 247267328); // 3*4 MiB

  // jax.random.split(key(42), 3), threefry_partitionable (foldlike) path:
  // child i = BOTH output words of threefry(key=(0,42), counter=(0,i))
  uint32_t d00,d01,d10,d11,d20,d21;
  tf2x32(0u, 42u, 0u, 0u, d00, d01);           // dk[0]
  tf2x32(0u, 42u, 0u, 1u, d10, d11);           // dk[1]
  tf2x32(0u, 42u, 0u, 2u, d20, d21);           // dk[2]

  cvt_x_p<<<26624, 256, 0, stream>>>(x, xpad);
  cvt_w_p<<<7810, 256, 0, stream>>>(W[0],W[1],W[2],W[3],W[4],W[5],W[6], WT1, WT);
  mask_gen_p<<<393216, 256, 0, stream>>>(masks, d00,d01, d10,d11, d20,d21);

  dim3 g(2048), b(256);
  gemm_p<false><<<g, b, 0, stream>>>(xpad, WT1,          B[0], nullptr,          1.0f,      hA, 832);
  gemm_p<true ><<<g, b, 0, stream>>>(hA,   WT + 0*262144, B[1], masks + 0*524288, 1.0f/0.8f, hB, 512);
  gemm_p<false><<<g, b, 0, stream>>>(hB,   WT + 1*262144, B[2], nullptr,          1.0f,      hA, 512);
  gemm_p<true ><<<g, b, 0, stream>>>(hA,   WT + 2*262144, B[3], masks + 1*524288, 1.0f/0.7f, hB, 512);
  gemm_p<false><<<g, b, 0, stream>>>(hB,   WT + 3*262144, B[4], nullptr,          1.0f,      hA, 512);
  gemm_p<true ><<<g, b, 0, stream>>>(hA,   WT + 4*262144, B[5], masks + 2*524288, 2.0f,      hB, 512);
  gemm_p<false><<<g, b, 0, stream>>>(hB,   WT + 5*262144, B[6], nullptr,          1.0f,      hA, 512);
  head_p<<<16384, 256, 0, stream>>>(hA, W[7], B[7], (float*)d_out);
}

// Round 5
// 702.102 us; speedup vs baseline: 1.4231x; 1.4231x over previous
//
#include <hip/hip_runtime.h>
#include <cstdint>

#define ROTL32(v,n) (((v) << (n)) | ((v) >> (32 - (n))))

// ---- JAX threefry-2x32 (20 rounds, exact key-injection schedule) ----
__host__ __device__ __forceinline__ void tf2x32(uint32_t k0, uint32_t k1,
                                                uint32_t x0, uint32_t x1,
                                                uint32_t& o0, uint32_t& o1)
{
  uint32_t k2 = k0 ^ k1 ^ 0x1BD11BDAu;
  x0 += k0; x1 += k1;
#define TF_RND(r) { x0 += x1; x1 = ROTL32(x1, (r)); x1 ^= x0; }
  TF_RND(13) TF_RND(15) TF_RND(26) TF_RND(6)
  x0 += k1; x1 += k2 + 1u;
  TF_RND(17) TF_RND(29) TF_RND(16) TF_RND(24)
  x0 += k2; x1 += k0 + 2u;
  TF_RND(13) TF_RND(15) TF_RND(26) TF_RND(6)
  x0 += k0; x1 += k1 + 3u;
  TF_RND(17) TF_RND(29) TF_RND(16) TF_RND(24)
  x0 += k1; x1 += k2 + 4u;
  TF_RND(13) TF_RND(15) TF_RND(26) TF_RND(6)
  x0 += k2; x1 += k0 + 5u;
#undef TF_RND
  o0 = x0; o1 = x1;
}

typedef __attribute__((ext_vector_type(8))) _Float16 h16x8;
typedef __attribute__((ext_vector_type(4))) float fl32x4;

__device__ __forceinline__ float u2unit_f(uint32_t b) {
  uint32_t r = (b >> 9) | 0x3F800000u;
  float f; __builtin_memcpy(&f, &r, 4); return f - 1.0f;
}

// async global->LDS, 16B per lane; LDS dest = wave-uniform base + lane*16 (m104)
#define GLD16(gp, lp) \
  __builtin_amdgcn_global_load_lds( \
      (__attribute__((address_space(1))) void*)(gp), \
      (__attribute__((address_space(3))) void*)(lp), 16, 0, 0)

// ---- x convert + pad (65536,784)f32 -> (65536,832)fp16, + produce L0 masks ----
__global__ __launch_bounds__(256) void cvt_x_f(const float* __restrict__ x,
                                               _Float16* __restrict__ xp,
                                               unsigned long long* __restrict__ m0,
                                               uint32_t k0, uint32_t k1)
{
  int idx = blockIdx.x * 256 + threadIdx.x;   // 65536*104 chunks of 8
  int row = idx / 104, c = idx - row * 104;
  h16x8 o = {0,0,0,0,0,0,0,0};
  if (c < 98) {
    const fl32x4* p = (const fl32x4*)&x[row * 784 + c * 8];
    fl32x4 a = p[0], b = p[1];
    o[0] = (_Float16)a[0]; o[1] = (_Float16)a[1]; o[2] = (_Float16)a[2]; o[3] = (_Float16)a[3];
    o[4] = (_Float16)b[0]; o[5] = (_Float16)b[1]; o[6] = (_Float16)b[2]; o[7] = (_Float16)b[3];
  }
  *(h16x8*)&xp[row * 832 + c * 8] = o;

  // L0 dropout masks (p=0.2): 524288 words over 106496 waves -> 5 words/wave
  uint32_t lane = threadIdx.x & 63u;
  uint32_t gw = (uint32_t)blockIdx.x * 4u + ((uint32_t)threadIdx.x >> 6);
#pragma unroll
  for (int i = 0; i < 5; ++i) {
    uint32_t wix = gw * 5u + (uint32_t)i;
    if (wix < 524288u) {                      // wave-uniform guard
      uint32_t b1, b2;
      tf2x32(k0, k1, 0u, wix * 64u + lane, b1, b2);
      unsigned long long mw = __ballot(u2unit_f(b1 ^ b2) < 0.8f);
      if (lane == 0) m0[wix] = mw;
    }
  }
}

// ---- weight transpose+convert: W(K,N) f32 -> WT(N,K) fp16 (W1 padded to K=832) ----
__global__ __launch_bounds__(256) void cvt_w_f(
    const float* __restrict__ W1, const float* __restrict__ W2, const float* __restrict__ W3,
    const float* __restrict__ W4, const float* __restrict__ W5, const float* __restrict__ W6,
    const float* __restrict__ W7, _Float16* __restrict__ WT1, _Float16* __restrict__ WT)
{
  int b = blockIdx.x;
  if (b < 1666) {                              // 512*832 = 426496 elems
    int idx = b * 256 + threadIdx.x;           // n*832 + k
    int n = idx / 832, k = idx - n * 832;
    WT1[idx] = (k < 784) ? (_Float16)W1[k * 512 + n] : (_Float16)0.f;
  } else {                                     // 6 layers of 512*512
    int l = (b - 1666) >> 10;
    int idx = ((b - 1666) & 1023) * 256 + threadIdx.x;
    int n = idx >> 9, k = idx & 511;
    const float* Wp = (l == 0) ? W2 : (l == 1) ? W3 : (l == 2) ? W4
                    : (l == 3) ? W5 : (l == 4) ? W6 : W7;
    WT[l * 262144 + idx] = (_Float16)Wp[k * 512 + n];
  }
}

// ---- 128x128 tile fp16 MFMA GEMM, C = relu(drop?(A@W + b)), A:MxK, BT:NxK ----
// Staging via global_load_lds w=16; optionally produces 32 mask words/wave for a
// LATER layer (threefry VALU fills the load-latency bubble before the barrier).
template<bool DROP>
__global__ __launch_bounds__(256) void gemm_f(
    const _Float16* __restrict__ A, const _Float16* __restrict__ BT,
    const float* __restrict__ bias, const unsigned long long* __restrict__ mask,
    float invq, _Float16* __restrict__ C, int K,
    unsigned long long* __restrict__ mout, uint32_t mbase,
    uint32_t mk0, uint32_t mk1, float mq)
{
  __shared__ __align__(16) _Float16 Als[128 * 64];
  __shared__ __align__(16) _Float16 Bls[128 * 64];
  int tid = threadIdx.x;
  int lane = tid & 63;
  int wv = tid >> 6;
  int wr = wv >> 1, wc = wv & 1;
  // bijective XCD swizzle: 2048 blocks, 8 XCDs, 256/XCD
  int lid = blockIdx.x;
  int t = (lid & 7) * 256 + (lid >> 3);
  int bm = (t >> 2) * 128;
  int bn = (t & 3) * 128;

  const _Float16* Ab = A + (size_t)bm * K;
  const _Float16* Bb = BT + (size_t)bn * K;

  fl32x4 acc[4][4];
#pragma unroll
  for (int i = 0; i < 4; ++i)
#pragma unroll
    for (int j = 0; j < 4; ++j)
      acc[i][j] = (fl32x4){0.f, 0.f, 0.f, 0.f};

  int nsteps = K >> 6;
  for (int kt = 0; kt < nsteps; ++kt) {
    // async stage: 1024 chunks of 16B; chunk id = p*256 + wv*64 + lane
    // LDS byte addr = id*16 (linear) -> dest = uniform base + lane*16  ✓
#pragma unroll
    for (int p = 0; p < 4; ++p) {
      int id  = p * 256 + wv * 64 + lane;
      int rowx = id >> 3, cc = id & 7;
      int gofs = rowx * K + kt * 64 + cc * 8;
      GLD16(Ab + gofs, &Als[(p * 256 + wv * 64) * 8]);
      GLD16(Bb + gofs, &Bls[(p * 256 + wv * 64) * 8]);
    }
    // mask production for a later layer: VALU work under the in-flight loads
    if (mout != nullptr && kt < 8) {
      uint32_t gw = (uint32_t)blockIdx.x * 4u + (uint32_t)wv;
#pragma unroll
      for (int i = 0; i < 4; ++i) {
        uint32_t wix = mbase + gw * 32u + (uint32_t)(kt * 4 + i);
        uint32_t b1, b2;
        tf2x32(mk0, mk1, 0u, wix * 64u + (uint32_t)lane, b1, b2);
        unsigned long long mw = __ballot(u2unit_f(b1 ^ b2) < mq);
        if (lane == 0) mout[wix] = mw;
      }
    }
    __syncthreads();                           // drains vmcnt -> tiles ready
#pragma unroll
    for (int kk = 0; kk < 2; ++kk) {
      int ko = kk * 32 + (lane >> 4) * 8;
      h16x8 af[4], bfr[4];
#pragma unroll
      for (int m = 0; m < 4; ++m)
        af[m] = *(const h16x8*)&Als[(wr * 64 + m * 16 + (lane & 15)) * 64 + ko];
#pragma unroll
      for (int n = 0; n < 4; ++n)
        bfr[n] = *(const h16x8*)&Bls[(wc * 64 + n * 16 + (lane & 15)) * 64 + ko];
#pragma unroll
      for (int m = 0; m < 4; ++m)
#pragma unroll
        for (int n = 0; n < 4; ++n)
          acc[m][n] = __builtin_amdgcn_mfma_f32_16x16x32_f16(af[m], bfr[n], acc[m][n], 0, 0, 0);
    }
    __syncthreads();
  }

  // epilogue: bias + (dropout) + relu -> fp16. C/D map: col=lane&15, row=(lane>>4)*4+reg
  int c0 = bn + wc * 64 + (lane & 15);
  int r0 = bm + wr * 64 + (lane >> 4) * 4;
#pragma unroll
  for (int n = 0; n < 4; ++n) {
    int col = c0 + n * 16;
    float bv = bias[col];
#pragma unroll
    for (int m = 0; m < 4; ++m) {
#pragma unroll
      for (int r = 0; r < 4; ++r) {
        int row = r0 + m * 16 + r;
        float v = acc[m][n][r] + bv;
        if (DROP) {
          uint32_t j = (uint32_t)row * 512u + (uint32_t)col;
          unsigned long long mw = mask[j >> 6];
          v = ((mw >> (j & 63)) & 1ull) ? v * invq : 0.0f;
        }
        v = fmaxf(v, 0.0f);
        C[(size_t)row * 512 + col] = (_Float16)v;
      }
    }
  }
}

// ---- head: logits = h@W8 + b8 (512->10), softmax, fp32 out ----
__global__ __launch_bounds__(256) void head_f(
    const _Float16* __restrict__ H, const float* __restrict__ W8,
    const float* __restrict__ b8, float* __restrict__ out)
{
  __shared__ float Wl[5120];                   // 512x10 fp32
  for (int i = threadIdx.x; i < 5120; i += 256) Wl[i] = W8[i];
  __syncthreads();
  int lane = threadIdx.x & 63;
  int wv = threadIdx.x >> 6;
  int row = blockIdx.x * 4 + wv;               // one row per wave
  h16x8 h = *(const h16x8*)&H[(size_t)row * 512 + lane * 8];
  float acc[10];
#pragma unroll
  for (int n = 0; n < 10; ++n) acc[n] = 0.f;
#pragma unroll
  for (int j = 0; j < 8; ++j) {
    float hf = (float)h[j];
    const float* wrow = &Wl[(lane * 8 + j) * 10];
#pragma unroll
    for (int n = 0; n < 10; ++n) acc[n] += hf * wrow[n];
  }
#pragma unroll
  for (int off = 1; off < 64; off <<= 1) {
#pragma unroll
    for (int n = 0; n < 10; ++n) acc[n] += __shfl_xor(acc[n], off);
  }
  if (lane == 0) {
    float mx = -3.0e38f;
#pragma unroll
    for (int n = 0; n < 10; ++n) { acc[n] += b8[n]; mx = fmaxf(mx, acc[n]); }
    float s = 0.f, e[10];
#pragma unroll
    for (int n = 0; n < 10; ++n) { e[n] = expf(acc[n] - mx); s += e[n]; }
    float is = 1.0f / s;
#pragma unroll
    for (int n = 0; n < 10; ++n) out[(size_t)row * 10 + n] = e[n] * is;
  }
}

extern "C" void kernel_launch(void* const* d_in, const int* in_sizes, int n_in,
                              void* d_out, int out_size, void* d_ws, size_t ws_size,
                              hipStream_t stream) {
  (void)in_sizes; (void)n_in; (void)out_size; (void)ws_size;
  const float* x = (const float*)d_in[0];
  const float* W[8]; const float* B[8];
  for (int i = 0; i < 8; ++i) { W[i] = (const float*)d_in[1 + 2*i]; B[i] = (const float*)d_in[2 + 2*i]; }

  char* w = (char*)d_ws;                       // ~260 MB total
  _Float16* xpad = (_Float16*)(w);             // 65536*832 fp16   = 109,051,904 B
  _Float16* hA   = (_Float16*)(w + 109051904); // 65536*512 fp16   =  67,108,864 B
  _Float16* hB   = (_Float16*)(w + 176160768); // 65536*512 fp16   =  67,108,864 B
  _Float16* WT1  = (_Float16*)(w + 243269632); // 512*832 fp16     =     851,968 B
  _Float16* WT   = (_Float16*)(w + 244121600); // 6 x 512*512 fp16 =   3,145,728 B
  unsigned long long* masks = (unsigned long long*)(w + 247267328); // 3*4 MiB
  unsigned long long* mL0 = masks;
  unsigned long long* mL1 = masks + 524288;
  unsigned long long* mL2 = masks + 1048576;

  // jax.random.split(key(42), 3), threefry_partitionable (foldlike) path:
  // child i = BOTH output words of threefry(key=(0,42), counter=(0,i))
  uint32_t d00,d01,d10,d11,d20,d21;
  tf2x32(0u, 42u, 0u, 0u, d00, d01);           // dk[0]  (p=0.2, q=0.8)
  tf2x32(0u, 42u, 0u, 1u, d10, d11);           // dk[1]  (p=0.3, q=0.7)
  tf2x32(0u, 42u, 0u, 2u, d20, d21);           // dk[2]  (p=0.5, q=0.5)
  (void)d00; (void)d01;

  cvt_x_f<<<26624, 256, 0, stream>>>(x, xpad, mL0, d00, d01);
  cvt_w_f<<<7810, 256, 0, stream>>>(W[0],W[1],W[2],W[3],W[4],W[5],W[6], WT1, WT);

  dim3 g(2048), b(256);
  // producer schedule: L0 in cvt_x; L1 halves in gemm#1/#2; L2 halves in gemm#3/#4
  gemm_f<false><<<g, b, 0, stream>>>(xpad, WT1,           B[0], nullptr, 1.0f,      hA, 832,
                                     mL1, 0u,      d10, d11, 0.7f);
  gemm_f<true ><<<g, b, 0, stream>>>(hA,   WT + 0*262144, B[1], mL0,     1.0f/0.8f, hB, 512,
                                     mL1, 262144u, d10, d11, 0.7f);
  gemm_f<false><<<g, b, 0, stream>>>(hB,   WT + 1*262144, B[2], nullptr, 1.0f,      hA, 512,
                                     mL2, 0u,      d20, d21, 0.5f);
  gemm_f<true ><<<g, b, 0, stream>>>(hA,   WT + 2*262144, B[3], mL1,     1.0f/0.7f, hB, 512,
                                     mL2, 262144u, d20, d21, 0.5f);
  gemm_f<false><<<g, b, 0, stream>>>(hB,   WT + 3*262144, B[4], nullptr, 1.0f,      hA, 512,
                                     nullptr, 0u, 0u, 0u, 0.f);
  gemm_f<true ><<<g, b, 0, stream>>>(hA,   WT + 4*262144, B[5], mL2,     2.0f,      hB, 512,
                                     nullptr, 0u, 0u, 0u, 0.f);
  gemm_f<false><<<g, b, 0, stream>>>(hB,   WT + 5*262144, B[6], nullptr, 1.0f,      hA, 512,
                                     nullptr, 0u, 0u, 0u, 0.f);
  head_f<<<16384, 256, 0, stream>>>(hA, W[7], B[7], (float*)d_out);
}

// Round 6
// 700.667 us; speedup vs baseline: 1.4261x; 1.0020x over previous
//
#include <hip/hip_runtime.h>
#include <cstdint>

#define ROTL32(v,n) (((v) << (n)) | ((v) >> (32 - (n))))

// ---- JAX threefry-2x32 (20 rounds, exact key-injection schedule) ----
__host__ __device__ __forceinline__ void tf2x32(uint32_t k0, uint32_t k1,
                                                uint32_t x0, uint32_t x1,
                                                uint32_t& o0, uint32_t& o1)
{
  uint32_t k2 = k0 ^ k1 ^ 0x1BD11BDAu;
  x0 += k0; x1 += k1;
#define TF_RND(r) { x0 += x1; x1 = ROTL32(x1, (r)); x1 ^= x0; }
  TF_RND(13) TF_RND(15) TF_RND(26) TF_RND(6)
  x0 += k1; x1 += k2 + 1u;
  TF_RND(17) TF_RND(29) TF_RND(16) TF_RND(24)
  x0 += k2; x1 += k0 + 2u;
  TF_RND(13) TF_RND(15) TF_RND(26) TF_RND(6)
  x0 += k0; x1 += k1 + 3u;
  TF_RND(17) TF_RND(29) TF_RND(16) TF_RND(24)
  x0 += k1; x1 += k2 + 4u;
  TF_RND(13) TF_RND(15) TF_RND(26) TF_RND(6)
  x0 += k2; x1 += k0 + 5u;
#undef TF_RND
  o0 = x0; o1 = x1;
}

typedef __attribute__((ext_vector_type(8))) _Float16 h16x8;
typedef __attribute__((ext_vector_type(4))) float fl32x4;

__device__ __forceinline__ float u2unit_f(uint32_t b) {
  uint32_t r = (b >> 9) | 0x3F800000u;
  float f; __builtin_memcpy(&f, &r, 4); return f - 1.0f;
}

// async global->LDS, 16B per lane; LDS dest = wave-uniform base + lane*16 (m104)
#define GLD16(gp, lp) \
  __builtin_amdgcn_global_load_lds( \
      (__attribute__((address_space(1))) void*)(gp), \
      (__attribute__((address_space(3))) void*)(lp), 16, 0, 0)

// ---- x convert + pad (65536,784)f32 -> (65536,832)fp16, + produce L0 masks ----
__global__ __launch_bounds__(256) void cvt_x_f(const float* __restrict__ x,
                                               _Float16* __restrict__ xp,
                                               unsigned long long* __restrict__ m0,
                                               uint32_t k0, uint32_t k1)
{
  int idx = blockIdx.x * 256 + threadIdx.x;   // 65536*104 chunks of 8
  int row = idx / 104, c = idx - row * 104;
  h16x8 o = {0,0,0,0,0,0,0,0};
  if (c < 98) {
    const fl32x4* p = (const fl32x4*)&x[row * 784 + c * 8];
    fl32x4 a = p[0], b = p[1];
    o[0] = (_Float16)a[0]; o[1] = (_Float16)a[1]; o[2] = (_Float16)a[2]; o[3] = (_Float16)a[3];
    o[4] = (_Float16)b[0]; o[5] = (_Float16)b[1]; o[6] = (_Float16)b[2]; o[7] = (_Float16)b[3];
  }
  *(h16x8*)&xp[row * 832 + c * 8] = o;

  // L0 dropout masks (p=0.2): 524288 words over 106496 waves -> 5 words/wave
  uint32_t lane = threadIdx.x & 63u;
  uint32_t gw = (uint32_t)blockIdx.x * 4u + ((uint32_t)threadIdx.x >> 6);
#pragma unroll
  for (int i = 0; i < 5; ++i) {
    uint32_t wix = gw * 5u + (uint32_t)i;
    if (wix < 524288u) {                      // wave-uniform guard
      uint32_t b1, b2;
      tf2x32(k0, k1, 0u, wix * 64u + lane, b1, b2);
      unsigned long long mw = __ballot(u2unit_f(b1 ^ b2) < 0.8f);
      if (lane == 0) m0[wix] = mw;
    }
  }
}

// ---- weight transpose+convert: W(K,N) f32 -> WT(N,K) fp16 (W1 padded to K=832) ----
__global__ __launch_bounds__(256) void cvt_w_f(
    const float* __restrict__ W1, const float* __restrict__ W2, const float* __restrict__ W3,
    const float* __restrict__ W4, const float* __restrict__ W5, const float* __restrict__ W6,
    const float* __restrict__ W7, _Float16* __restrict__ WT1, _Float16* __restrict__ WT)
{
  int b = blockIdx.x;
  if (b < 1666) {                              // 512*832 = 426496 elems
    int idx = b * 256 + threadIdx.x;           // n*832 + k
    int n = idx / 832, k = idx - n * 832;
    WT1[idx] = (k < 784) ? (_Float16)W1[k * 512 + n] : (_Float16)0.f;
  } else {                                     // 6 layers of 512*512
    int l = (b - 1666) >> 10;
    int idx = ((b - 1666) & 1023) * 256 + threadIdx.x;
    int n = idx >> 9, k = idx & 511;
    const float* Wp = (l == 0) ? W2 : (l == 1) ? W3 : (l == 2) ? W4
                    : (l == 3) ? W5 : (l == 4) ? W6 : W7;
    WT[l * 262144 + idx] = (_Float16)Wp[k * 512 + n];
  }
}

// ---- 128x128 tile fp16 MFMA GEMM, C = relu(drop?(A@W + b)), A:MxK, BT:NxK ----
// Double-buffered LDS + global_load_lds prefetch (T3-minimal): next k-tile's
// loads are issued BEFORE computing the current tile; the single barrier per
// step drains them a full compute-phase later. LDS is XOR-swizzled via
// pre-swizzled GLOBAL source (linear dest, rule 21) + swizzled ds_read.
template<bool DROP>
__global__ __launch_bounds__(256) void gemm_f(
    const _Float16* __restrict__ A, const _Float16* __restrict__ BT,
    const float* __restrict__ bias, const unsigned long long* __restrict__ mask,
    float invq, _Float16* __restrict__ C, int K,
    unsigned long long* __restrict__ mout, uint32_t mbase,
    uint32_t mk0, uint32_t mk1, float mq)
{
  __shared__ __align__(16) _Float16 Als[2][128 * 64];
  __shared__ __align__(16) _Float16 Bls[2][128 * 64];
  int tid = threadIdx.x;
  int lane = tid & 63;
  int wv = tid >> 6;
  int wr = wv >> 1, wc = wv & 1;
  // bijective XCD swizzle: 2048 blocks, 8 XCDs, 256/XCD
  int lid = blockIdx.x;
  int t = (lid & 7) * 256 + (lid >> 3);
  int bm = (t >> 2) * 128;
  int bn = (t & 3) * 128;

  const _Float16* Ab = A + (size_t)bm * K;
  const _Float16* Bb = BT + (size_t)bn * K;

  // staging geometry: chunk id = p*256 + wv*64 + lane; LDS dest linear (id*16B).
  // inverse source swizzle: within-row 16B slot cs = (lane&7) ^ ((lane>>3)&7)
  int swz_cs = (lane & 7) ^ ((lane >> 3) & 7);

  fl32x4 acc[4][4];
#pragma unroll
  for (int i = 0; i < 4; ++i)
#pragma unroll
    for (int j = 0; j < 4; ++j)
      acc[i][j] = (fl32x4){0.f, 0.f, 0.f, 0.f};

  int nsteps = K >> 6;

#define STAGE(buf, kt)                                                        \
  {                                                                           \
    _Pragma("unroll")                                                         \
    for (int p = 0; p < 4; ++p) {                                             \
      int id   = p * 256 + wv * 64 + lane;                                    \
      int rowx = id >> 3;                                                     \
      int gofs = rowx * K + (kt) * 64 + swz_cs * 8;                           \
      GLD16(Ab + gofs, &Als[buf][(p * 256 + wv * 64) * 8]);                   \
      GLD16(Bb + gofs, &Bls[buf][(p * 256 + wv * 64) * 8]);                   \
    }                                                                         \
  }

  STAGE(0, 0);
  __syncthreads();                             // drains vmcnt -> buf0 ready
  int cb = 0;
  for (int kt = 0; kt < nsteps; ++kt) {
    if (kt + 1 < nsteps) STAGE(cb ^ 1, kt + 1);    // prefetch next tile
    // mask production for a later layer: VALU under the in-flight loads
    if (mout != nullptr && kt < 8) {
      uint32_t gw = (uint32_t)blockIdx.x * 4u + (uint32_t)wv;
#pragma unroll
      for (int i = 0; i < 4; ++i) {
        uint32_t wix = mbase + gw * 32u + (uint32_t)(kt * 4 + i);
        uint32_t b1, b2;
        tf2x32(mk0, mk1, 0u, wix * 64u + (uint32_t)lane, b1, b2);
        unsigned long long mw = __ballot(u2unit_f(b1 ^ b2) < mq);
        if (lane == 0) mout[wix] = mw;
      }
    }
    // compute current buffer; reads XOR-swizzled: elem ^= (lane&7)<<3
    int rsw = (lane & 7) << 3;
#pragma unroll
    for (int kk = 0; kk < 2; ++kk) {
      int ko = kk * 32 + (lane >> 4) * 8;
      h16x8 af[4], bfr[4];
#pragma unroll
      for (int m = 0; m < 4; ++m)
        af[m] = *(const h16x8*)&Als[cb][((wr * 64 + m * 16 + (lane & 15)) * 64 + ko) ^ rsw];
#pragma unroll
      for (int n = 0; n < 4; ++n)
        bfr[n] = *(const h16x8*)&Bls[cb][((wc * 64 + n * 16 + (lane & 15)) * 64 + ko) ^ rsw];
#pragma unroll
      for (int m = 0; m < 4; ++m)
#pragma unroll
        for (int n = 0; n < 4; ++n)
          acc[m][n] = __builtin_amdgcn_mfma_f32_16x16x32_f16(af[m], bfr[n], acc[m][n], 0, 0, 0);
    }
    __syncthreads();                           // drains prefetch; guards buf reuse
    cb ^= 1;
  }
#undef STAGE

  // epilogue: bias + (dropout) + relu -> fp16. C/D map: col=lane&15, row=(lane>>4)*4+reg
  int c0 = bn + wc * 64 + (lane & 15);
  int r0 = bm + wr * 64 + (lane >> 4) * 4;
#pragma unroll
  for (int n = 0; n < 4; ++n) {
    int col = c0 + n * 16;
    float bv = bias[col];
#pragma unroll
    for (int m = 0; m < 4; ++m) {
#pragma unroll
      for (int r = 0; r < 4; ++r) {
        int row = r0 + m * 16 + r;
        float v = acc[m][n][r] + bv;
        if (DROP) {
          uint32_t j = (uint32_t)row * 512u + (uint32_t)col;
          unsigned long long mw = mask[j >> 6];
          v = ((mw >> (j & 63)) & 1ull) ? v * invq : 0.0f;
        }
        v = fmaxf(v, 0.0f);
        C[(size_t)row * 512 + col] = (_Float16)v;
      }
    }
  }
}

// ---- head: logits = h@W8 + b8 (512->10), softmax, fp32 out ----
__global__ __launch_bounds__(256) void head_f(
    const _Float16* __restrict__ H, const float* __restrict__ W8,
    const float* __restrict__ b8, float* __restrict__ out)
{
  __shared__ float Wl[5120];                   // 512x10 fp32
  for (int i = threadIdx.x; i < 5120; i += 256) Wl[i] = W8[i];
  __syncthreads();
  int lane = threadIdx.x & 63;
  int wv = threadIdx.x >> 6;
  int row = blockIdx.x * 4 + wv;               // one row per wave
  h16x8 h = *(const h16x8*)&H[(size_t)row * 512 + lane * 8];
  float acc[10];
#pragma unroll
  for (int n = 0; n < 10; ++n) acc[n] = 0.f;
#pragma unroll
  for (int j = 0; j < 8; ++j) {
    float hf = (float)h[j];
    const float* wrow = &Wl[(lane * 8 + j) * 10];
#pragma unroll
    for (int n = 0; n < 10; ++n) acc[n] += hf * wrow[n];
  }
#pragma unroll
  for (int off = 1; off < 64; off <<= 1) {
#pragma unroll
    for (int n = 0; n < 10; ++n) acc[n] += __shfl_xor(acc[n], off);
  }
  if (lane == 0) {
    float mx = -3.0e38f;
#pragma unroll
    for (int n = 0; n < 10; ++n) { acc[n] += b8[n]; mx = fmaxf(mx, acc[n]); }
    float s = 0.f, e[10];
#pragma unroll
    for (int n = 0; n < 10; ++n) { e[n] = expf(acc[n] - mx); s += e[n]; }
    float is = 1.0f / s;
#pragma unroll
    for (int n = 0; n < 10; ++n) out[(size_t)row * 10 + n] = e[n] * is;
  }
}

extern "C" void kernel_launch(void* const* d_in, const int* in_sizes, int n_in,
                              void* d_out, int out_size, void* d_ws, size_t ws_size,
                              hipStream_t stream) {
  (void)in_sizes; (void)n_in; (void)out_size; (void)ws_size;
  const float* x = (const float*)d_in[0];
  const float* W[8]; const float* B[8];
  for (int i = 0; i < 8; ++i) { W[i] = (const float*)d_in[1 + 2*i]; B[i] = (const float*)d_in[2 + 2*i]; }

  char* w = (char*)d_ws;                       // ~260 MB total
  _Float16* xpad = (_Float16*)(w);             // 65536*832 fp16   = 109,051,904 B
  _Float16* hA   = (_Float16*)(w + 109051904); // 65536*512 fp16   =  67,108,864 B
  _Float16* hB   = (_Float16*)(w + 176160768); // 65536*512 fp16   =  67,108,864 B
  _Float16* WT1  = (_Float16*)(w + 243269632); // 512*832 fp16     =     851,968 B
  _Float16* WT   = (_Float16*)(w + 244121600); // 6 x 512*512 fp16 =   3,145,728 B
  unsigned long long* masks = (unsigned long long*)(w + 247267328); // 3*4 MiB
  unsigned long long* mL0 = masks;
  unsigned long long* mL1 = masks + 524288;
  unsigned long long* mL2 = masks + 1048576;

  // jax.random.split(key(42), 3), threefry_partitionable (foldlike) path:
  // child i = BOTH output words of threefry(key=(0,42), counter=(0,i))
  uint32_t d00,d01,d10,d11,d20,d21;
  tf2x32(0u, 42u, 0u, 0u, d00, d01);           // dk[0]  (p=0.2, q=0.8)
  tf2x32(0u, 42u, 0u, 1u, d10, d11);           // dk[1]  (p=0.3, q=0.7)
  tf2x32(0u, 42u, 0u, 2u, d20, d21);           // dk[2]  (p=0.5, q=0.5)

  cvt_x_f<<<26624, 256, 0, stream>>>(x, xpad, mL0, d00, d01);
  cvt_w_f<<<7810, 256, 0, stream>>>(W[0],W[1],W[2],W[3],W[4],W[5],W[6], WT1, WT);

  dim3 g(2048), b(256);
  // producer schedule: L0 in cvt_x; L1 halves in gemm#1/#2; L2 halves in gemm#3/#4
  gemm_f<false><<<g, b, 0, stream>>>(xpad, WT1,           B[0], nullptr, 1.0f,      hA, 832,
                                     mL1, 0u,      d10, d11, 0.7f);
  gemm_f<true ><<<g, b, 0, stream>>>(hA,   WT + 0*262144, B[1], mL0,     1.0f/0.8f, hB, 512,
                                     mL1, 262144u, d10, d11, 0.7f);
  gemm_f<false><<<g, b, 0, stream>>>(hB,   WT + 1*262144, B[2], nullptr, 1.0f,      hA, 512,
                                     mL2, 0u,      d20, d21, 0.5f);
  gemm_f<true ><<<g, b, 0, stream>>>(hA,   WT + 2*262144, B[3], mL1,     1.0f/0.7f, hB, 512,
                                     mL2, 262144u, d20, d21, 0.5f);
  gemm_f<false><<<g, b, 0, stream>>>(hB,   WT + 3*262144, B[4], nullptr, 1.0f,      hA, 512,
                                     nullptr, 0u, 0u, 0u, 0.f);
  gemm_f<true ><<<g, b, 0, stream>>>(hA,   WT + 4*262144, B[5], mL2,     2.0f,      hB, 512,
                                     nullptr, 0u, 0u, 0u, 0.f);
  gemm_f<false><<<g, b, 0, stream>>>(hB,   WT + 5*262144, B[6], nullptr, 1.0f,      hA, 512,
                                     nullptr, 0u, 0u, 0u, 0.f);
  head_f<<<16384, 256, 0, stream>>>(hA, W[7], B[7], (float*)d_out);
}